// Round 14
// baseline (652.421 us; speedup 1.0000x reference)
//
#include <hip/hip_runtime.h>
#include <hip/hip_bf16.h>
#include <cstddef>
#include <cstdint>

#define NN 150000
#define EP 400000
#define EN 200000
#define SCAN_BS 256

typedef __bf16 bf16x8 __attribute__((ext_vector_type(8)));
typedef float  f32x4  __attribute__((ext_vector_type(4)));

__device__ __forceinline__ float fast_tanh(float x) {
    float e = __expf(2.f * x);
    return 1.f - 2.f / (e + 1.f);
}

__device__ __forceinline__ void async16(const void* g, void* l) {
    __builtin_amdgcn_global_load_lds(
        (const __attribute__((address_space(1))) void*)g,
        (__attribute__((address_space(3))) void*)l, 16, 0, 0);
}

// ---------------- counts ----------------
__global__ void count_kernel(const int* __restrict__ dst, int E, int* __restrict__ cnt) {
    int e = blockIdx.x * blockDim.x + threadIdx.x;
    if (e < E) atomicAdd(&cnt[dst[e]], 1);
}

// ---------------- exclusive scan (3-kernel) ----------------
__global__ void scan_block(const int* __restrict__ cnt, int n,
                           int* __restrict__ excl, int* __restrict__ bsum) {
    __shared__ int lds[SCAN_BS];
    int tid = threadIdx.x;
    int i = blockIdx.x * SCAN_BS + tid;
    int v = (i < n) ? cnt[i] : 0;
    lds[tid] = v;
    __syncthreads();
    for (int d = 1; d < SCAN_BS; d <<= 1) {
        int t = (tid >= d) ? lds[tid - d] : 0;
        __syncthreads();
        lds[tid] += t;
        __syncthreads();
    }
    if (i < n) excl[i] = lds[tid] - v;
    if (tid == SCAN_BS - 1) bsum[blockIdx.x] = lds[tid];
}

__global__ void scan_bsum(int* __restrict__ bsum, int nb) {
    __shared__ int lds[SCAN_BS];
    __shared__ int carry;
    int tid = threadIdx.x;
    if (tid == 0) carry = 0;
    __syncthreads();
    for (int base = 0; base < nb; base += SCAN_BS) {
        int i = base + tid;
        int v = (i < nb) ? bsum[i] : 0;
        lds[tid] = v;
        __syncthreads();
        for (int d = 1; d < SCAN_BS; d <<= 1) {
            int t = (tid >= d) ? lds[tid - d] : 0;
            __syncthreads();
            lds[tid] += t;
            __syncthreads();
        }
        if (i < nb) bsum[i] = lds[tid] - v + carry;
        __syncthreads();
        if (tid == 0) carry += lds[SCAN_BS - 1];
        __syncthreads();
    }
}

__global__ void scan_add(const int* __restrict__ bsum, int n,
                         int* __restrict__ excl, int* __restrict__ cur) {
    int i = blockIdx.x * SCAN_BS + threadIdx.x;
    if (i < n) {
        int o = excl[i] + bsum[blockIdx.x];
        excl[i] = o;
        cur[i] = o;
    }
}

__global__ void fill_csr(const int* __restrict__ src, const int* __restrict__ dst, int E,
                         int* __restrict__ cur, int* __restrict__ csr) {
    int e = blockIdx.x * blockDim.x + threadIdx.x;
    if (e < E) {
        int d = dst[e];
        int p = atomicAdd(&cur[d], 1);
        csr[p] = src[e];
    }
}

// ---------------- weight prep (incl. algebraic fusion of layer-1) ----------------
__global__ void prep_weights(const float* __restrict__ W_in, const float* __restrict__ b_in,
                             const float* __restrict__ W1p, const float* __restrict__ b1p,
                             const float* __restrict__ W1n, const float* __restrict__ b1n,
                             const float* __restrict__ W2p, const float* __restrict__ b2p,
                             const float* __restrict__ W2n, const float* __restrict__ b2n,
                             const float* __restrict__ Wz,  const float* __restrict__ Wm1,
                             const float* __restrict__ Wm2,
                             __hip_bfloat16* __restrict__ Wc1t,  // [128][64]
                             __hip_bfloat16* __restrict__ Wc2t,  // [128][64]
                             float* __restrict__ bc1, float* __restrict__ bc2,
                             __hip_bfloat16* __restrict__ Wt2,   // [128][384]
                             __hip_bfloat16* __restrict__ WtZ,
                             __hip_bfloat16* __restrict__ WtM1,
                             __hip_bfloat16* __restrict__ WtM2,
                             float* __restrict__ b2cat) {
    int idx = blockIdx.x * blockDim.x + threadIdx.x;
    if (idx < 128 * 64) {
        int c = idx >> 6, k = idx & 63;
        float s1 = 0.f, s2 = 0.f;
#pragma unroll 4
        for (int j = 0; j < 128; ++j) {
            float w = W_in[k * 128 + j];
            float wc = (c < 64) ? W1p[j * 64 + c] : W1n[j * 64 + (c - 64)];
            float wl = (c < 64) ? W1p[(128 + j) * 64 + c] : W1n[(128 + j) * 64 + (c - 64)];
            s1 += w * wc;
            s2 += w * wl;
        }
        Wc1t[idx] = __float2bfloat16(s1);
        Wc2t[idx] = __float2bfloat16(s2);
    }
    if (idx < 128 * 128) {
        int c = idx >> 7, k = idx & 127;
        WtZ[idx]  = __float2bfloat16(Wz[k * 128 + c]);
        WtM1[idx] = __float2bfloat16(Wm1[k * 128 + c]);
        WtM2[idx] = __float2bfloat16(Wm2[k * 128 + c]);
    }
    if (idx < 128 * 384) {
        int c = idx / 384, r = idx % 384;
        float v = 0.f;
        if (r < 64)       { if (c < 64)  v = W2p[r * 64 + c]; }
        else if (r < 128) { if (c >= 64) v = W2n[(r - 64) * 64 + (c - 64)]; }
        else if (r < 192) { if (c >= 64) v = W2n[(64 + r - 128) * 64 + (c - 64)]; }
        else if (r < 256) { if (c < 64)  v = W2p[(64 + r - 192) * 64 + c]; }
        else if (r < 320) { if (c < 64)  v = W2p[(128 + r - 256) * 64 + c]; }
        else              { if (c >= 64) v = W2n[(128 + r - 320) * 64 + (c - 64)]; }
        Wt2[idx] = __float2bfloat16(v);
    }
    if (idx < 128) {
        int c = idx;
        float s1 = 0.f, s2 = 0.f;
#pragma unroll 4
        for (int j = 0; j < 128; ++j) {
            float b = b_in[j];
            float wc = (c < 64) ? W1p[j * 64 + c] : W1n[j * 64 + (c - 64)];
            float wl = (c < 64) ? W1p[(128 + j) * 64 + c] : W1n[(128 + j) * 64 + (c - 64)];
            s1 += b * wc;
            s2 += b * wl;
        }
        bc1[c] = s1;
        bc2[c] = s2 + ((c < 64) ? b1p[c] : b1n[c - 64]);
        b2cat[c] = (c < 64) ? b2p[c] : b2n[c - 64];
    }
}

// ========== GEMM0: x -> U1 (x@Wc1+bc1) AND V2 (x@Wc2+bc2), one A-staging ==========
__global__ __launch_bounds__(256, 2) void gemm0(
    const float* __restrict__ x,
    const __hip_bfloat16* __restrict__ Wc1t, const float* __restrict__ bc1,
    const __hip_bfloat16* __restrict__ Wc2t, const float* __restrict__ bc2,
    __hip_bfloat16* __restrict__ U1, __hip_bfloat16* __restrict__ V2,
    int n, int nt, int grid)
{
    __shared__ __align__(16) char w1lds[1024 * 16];   // 16KB each
    __shared__ __align__(16) char w2lds[1024 * 16];
    __shared__ __align__(16) char alds[2][1024 * 16]; // f32 A tiles, dbuf
    const int tid = threadIdx.x, lane = tid & 63, wv = tid >> 6;
    const int l16 = lane & 15, lhi = lane >> 4;

    // stage both W's once (K=64, NFC=2): slot f = c*2+kk
#pragma unroll
    for (int i = 0; i < 4; ++i) {
        int slot = tid + i * 256;
        int ln = slot & 63, f = slot >> 6;
        int c = f >> 1, kk = f & 1;
        int row = c * 16 + (ln & 15);
        int gk = kk * 32 + (ln >> 4) * 8;
        async16(Wc1t + (size_t)row * 64 + gk, w1lds + slot * 16);
        async16(Wc2t + (size_t)row * 64 + gk, w2lds + slot * 16);
    }

    auto stageA = [&](int tile, int bufi) {
        char* dst = alds[bufi];
#pragma unroll
        for (int i = 0; i < 4; ++i) {
            int slot = tid + i * 256;
            int ln = slot & 63, f = slot >> 6;
            int w = f >> 2, kk = (f >> 1) & 1, half = f & 1;
            int row = tile * 64 + w * 16 + (ln & 15);
            if (row > n - 1) row = n - 1;
            int k = kk * 32 + (ln >> 4) * 8 + half * 4;
            async16(x + (size_t)row * 64 + k, dst + slot * 16);
        }
    };

    auto computeT = [&](int tile, int bufi) {
        const char* ab = alds[bufi];
        bf16x8 afr[2];
#pragma unroll
        for (int kk = 0; kk < 2; ++kk) {
            f32x4 lo = *reinterpret_cast<const f32x4*>(
                ab + ((((wv * 2 + kk) * 2 + 0) * 64 + lane) << 4));
            f32x4 hi = *reinterpret_cast<const f32x4*>(
                ab + ((((wv * 2 + kk) * 2 + 1) * 64 + lane) << 4));
            bf16x8 a;
            a[0] = (__bf16)lo[0]; a[1] = (__bf16)lo[1];
            a[2] = (__bf16)lo[2]; a[3] = (__bf16)lo[3];
            a[4] = (__bf16)hi[0]; a[5] = (__bf16)hi[1];
            a[6] = (__bf16)hi[2]; a[7] = (__bf16)hi[3];
            afr[kk] = a;
        }
        const int brow = tile * 64 + wv * 16;
#pragma unroll
        for (int half = 0; half < 2; ++half) {
            const char* wl = half ? w2lds : w1lds;
            const float* bias = half ? bc2 : bc1;
            __hip_bfloat16* out = half ? V2 : U1;
            f32x4 acc[8];
#pragma unroll
            for (int c = 0; c < 8; ++c)
#pragma unroll
                for (int i = 0; i < 4; ++i) acc[c][i] = 0.f;
#pragma unroll
            for (int kk = 0; kk < 2; ++kk)
#pragma unroll
                for (int c = 0; c < 8; ++c) {
                    bf16x8 b = *reinterpret_cast<const bf16x8*>(
                        wl + (((c * 2 + kk) * 64 + lane) << 4));
                    acc[c] = __builtin_amdgcn_mfma_f32_16x16x32_bf16(afr[kk], b, acc[c], 0, 0, 0);
                }
#pragma unroll
            for (int c = 0; c < 8; ++c) {
                int col = c * 16 + l16;
                float bv = bias[col];
#pragma unroll
                for (int r = 0; r < 4; ++r) {
                    int grow = brow + lhi * 4 + r;
                    if (grow < n)
                        out[(size_t)grow * 128 + col] = __float2bfloat16(acc[c][r] + bv);
                }
            }
        }
    };

    int t = blockIdx.x;
    stageA(t, 0);
    __syncthreads();
    int cur = 0;
    for (; t < nt; t += grid) {
        int tn = t + grid;
        if (tn < nt) stageA(tn, cur ^ 1);
        computeT(t, cur);
        __syncthreads();
        cur ^= 1;
    }
}

// ======= gather1z: z1 = tanh(aggC + V2), aggC gathered from U1 via CSR =======
__global__ void gather1z(const __hip_bfloat16* __restrict__ U1,
                         const __hip_bfloat16* __restrict__ V2,
                         const int* __restrict__ offp, const int* __restrict__ cntp,
                         const int* __restrict__ csrp,
                         const int* __restrict__ offn, const int* __restrict__ cntn,
                         const int* __restrict__ csrn,
                         __hip_bfloat16* __restrict__ z1) {
    int gid = blockIdx.x * blockDim.x + threadIdx.x;
    if (gid >= NN * 16) return;
    int d = gid >> 4, cg = gid & 15;
    int c0 = cg * 8;
    const int* off; const int* cnt; const int* csr;
    if (cg < 8) { off = offp; cnt = cntp; csr = csrp; }
    else        { off = offn; cnt = cntn; csr = csrn; }
    int o = off[d], dg = cnt[d];
    float acc[8] = {0.f, 0.f, 0.f, 0.f, 0.f, 0.f, 0.f, 0.f};
    for (int e = 0; e < dg; ++e) {
        int s = csr[o + e];
        bf16x8 v = *reinterpret_cast<const bf16x8*>(&U1[(size_t)s * 128 + c0]);
#pragma unroll
        for (int j = 0; j < 8; ++j) acc[j] += (float)v[j];
    }
    float inv = 1.f / (float)(dg > 0 ? dg : 1);
    bf16x8 v2 = *reinterpret_cast<const bf16x8*>(&V2[(size_t)d * 128 + c0]);
    bf16x8 r;
#pragma unroll
    for (int j = 0; j < 8; ++j)
        r[j] = (__bf16)fast_tanh(acc[j] * inv + (float)v2[j]);
    *reinterpret_cast<bf16x8*>(&z1[(size_t)d * 128 + c0]) = r;
}

// ========= chainAg: per 64-row tile: gather P,Q (LDS) -> z2 -> z -> M1 =========
// P,Q never touch global memory. z2/z in swizzled LDS. W restaged per phase (L2-hot).
__global__ __launch_bounds__(256, 2) void chainAg(
    const __hip_bfloat16* __restrict__ z1,
    const int* __restrict__ offp, const int* __restrict__ cntp, const int* __restrict__ csrp,
    const int* __restrict__ offn, const int* __restrict__ cntn, const int* __restrict__ csrn,
    const __hip_bfloat16* __restrict__ Wt2, const float* __restrict__ b2cat,
    const __hip_bfloat16* __restrict__ WtZ, const float* __restrict__ bz,
    const __hip_bfloat16* __restrict__ WtM1, const float* __restrict__ bm1,
    double* __restrict__ stats1, float* __restrict__ zout,
    __hip_bfloat16* __restrict__ m1B, int n, int nt, int grid)
{
    __shared__ __align__(16) char wlds[2048 * 16];  // 32KB
    __shared__ __align__(16) char plds[64 * 256];   // 16KB gathered P tile (swizzled)
    __shared__ __align__(16) char qlds[64 * 256];   // 16KB gathered Q tile
    __shared__ __align__(16) char zlds[64 * 256];   // 16KB z2 then z
    __shared__ float ssum[128], ssq[128];
    const int tid = threadIdx.x, lane = tid & 63, wv = tid >> 6;
    const int l16 = lane & 15, lhi = lane >> 4;
    if (tid < 128) { ssum[tid] = 0.f; ssq[tid] = 0.f; }

    auto stageW = [&](const __hip_bfloat16* Wt, int ks, int k0) {
#pragma unroll
        for (int i = 0; i < 8; ++i) {
            int slot = tid + i * 256;
            int ln = slot & 63, f = slot >> 6;
            int c = f >> 2, kk = f & 3;
            int row = c * 16 + (ln & 15);
            int gk = k0 + kk * 32 + (ln >> 4) * 8;
            async16(Wt + (size_t)row * ks + gk, wlds + slot * 16);
        }
    };
    auto domfma = [&](const bf16x8 (&af)[4], f32x4 (&acc)[8]) {
#pragma unroll
        for (int kk = 0; kk < 4; ++kk)
#pragma unroll
            for (int c = 0; c < 8; ++c) {
                bf16x8 b = *reinterpret_cast<const bf16x8*>(
                    wlds + (((c * 4 + kk) * 64 + lane) << 4));
                acc[c] = __builtin_amdgcn_mfma_f32_16x16x32_bf16(af[kk], b, acc[c], 0, 0, 0);
            }
    };
    auto zacc = [&](f32x4 (&acc)[8]) {
#pragma unroll
        for (int c = 0; c < 8; ++c)
#pragma unroll
            for (int i = 0; i < 4; ++i) acc[c][i] = 0.f;
    };
    // fragment load from a swizzled [64][256B] tile: own row rl = wv*16+l16
    auto ld_t = [&](const char* buf, bf16x8 (&af)[4]) {
        int rl = wv * 16 + l16;
#pragma unroll
        for (int kk = 0; kk < 4; ++kk) {
            int byte = rl * 256 + ((kk * 64 + lhi * 16) ^ ((rl & 7) << 4));
            af[kk] = *reinterpret_cast<const bf16x8*>(buf + byte);
        }
    };
    auto st_z = [&](int rl, int col, float v) {
        int byte = rl * 256 + ((col * 2) ^ ((rl & 7) << 4));
        *reinterpret_cast<__hip_bfloat16*>(zlds + byte) = __float2bfloat16(v);
    };

    bf16x8 af[4];
    f32x4 acc[8];

    for (int t = blockIdx.x; t < nt; t += grid) {
        __syncthreads();                 // prev tile's wlds/zlds/plds reads done

        // ---- phase a: stage W chunk0 (async) + gather P,Q into LDS ----
        stageW(Wt2, 384, 0);
#pragma unroll
        for (int it = 0; it < 8; ++it) {
            int i = tid + it * 256;       // 0..2047
            int set = i >> 10;            // 0 = P(pos), 1 = Q(neg)
            int rem = i & 1023;
            int r = rem >> 4;             // 0..63
            int cg = rem & 15, c0 = cg * 8;
            int d = t * 64 + r;
            float a8[8] = {0.f, 0.f, 0.f, 0.f, 0.f, 0.f, 0.f, 0.f};
            int dgc = 1;
            if (d < n) {
                const int* off = set ? offn : offp;
                const int* cnt = set ? cntn : cntp;
                const int* csr = set ? csrn : csrp;
                int o = off[d], dg = cnt[d];
                for (int e = 0; e < dg; ++e) {
                    int s = csr[o + e];
                    bf16x8 v = *reinterpret_cast<const bf16x8*>(&z1[(size_t)s * 128 + c0]);
#pragma unroll
                    for (int j = 0; j < 8; ++j) a8[j] += (float)v[j];
                }
                if (dg > 0) dgc = dg;
            }
            float inv = 1.f / (float)dgc;
            bf16x8 rr;
#pragma unroll
            for (int j = 0; j < 8; ++j) rr[j] = (__bf16)(a8[j] * inv);
            char* buf = set ? qlds : plds;
            int byte = r * 256 + ((c0 * 2) ^ ((r & 7) << 4));
            *reinterpret_cast<bf16x8*>(buf + byte) = rr;
        }
        // tile's own z1 rows (third K-segment A-frags), direct from global
        int arow = t * 64 + wv * 16 + l16; if (arow > n - 1) arow = n - 1;
        bf16x8 aZ[4];
#pragma unroll
        for (int kk = 0; kk < 4; ++kk)
            aZ[kk] = *reinterpret_cast<const bf16x8*>(z1 + (size_t)arow * 128 + kk * 32 + lhi * 8);
        __syncthreads();                 // drains stageW chunk0 + gather LDS writes

        // ---- phase b: z2 = tanh([P|Q|z1] @ Wt2 + b2cat) -> zlds ----
        zacc(acc);
        ld_t(plds, af);
        domfma(af, acc);
        __syncthreads();
        stageW(Wt2, 384, 128);
        __syncthreads();
        ld_t(qlds, af);
        domfma(af, acc);
        __syncthreads();
        stageW(Wt2, 384, 256);
        __syncthreads();
        domfma(aZ, acc);
#pragma unroll
        for (int c = 0; c < 8; ++c) {
            int col = c * 16 + l16;
            float bv = b2cat[col];
#pragma unroll
            for (int r = 0; r < 4; ++r)
                st_z(wv * 16 + lhi * 4 + r, col, fast_tanh(acc[c][r] + bv));
        }
        __syncthreads();                 // wlds reads done before restage

        // ---- phase c: z = tanh(z2 @ WtZ + bz) -> zout (f32) + zlds ----
        zacc(acc);
        stageW(WtZ, 128, 0);
        ld_t(zlds, af);
        __syncthreads();
        domfma(af, acc);
#pragma unroll
        for (int c = 0; c < 8; ++c) {
            int col = c * 16 + l16;
            float bv = bz[col];
#pragma unroll
            for (int r = 0; r < 4; ++r) {
                int rl = wv * 16 + lhi * 4 + r;
                int grow = t * 64 + rl;
                float v = fast_tanh(acc[c][r] + bv);
                if (grow < n) zout[(size_t)grow * 128 + col] = v;
                st_z(rl, col, v);        // own strip; own frag reads already done
            }
        }
        __syncthreads();                 // wlds reads done before restage

        // ---- phase d: M1 = z @ WtM1 + bm1 -> m1B + stats ----
        zacc(acc);
        stageW(WtM1, 128, 0);
        ld_t(zlds, af);
        __syncthreads();
        domfma(af, acc);
#pragma unroll
        for (int c = 0; c < 8; ++c) {
            int col = c * 16 + l16;
            float bv = bm1[col];
            float s = 0.f, q = 0.f;
#pragma unroll
            for (int r = 0; r < 4; ++r) {
                int rl = wv * 16 + lhi * 4 + r;
                int grow = t * 64 + rl;
                float v = acc[c][r] + bv;
                if (grow < n) {
                    m1B[(size_t)grow * 128 + col] = __float2bfloat16(v);
                    s += v; q += v * v;
                }
            }
            atomicAdd(&ssum[col], s);
            atomicAdd(&ssq[col], q);
        }
    }
    __syncthreads();
    if (tid < 128) {
        atomicAdd(&stats1[tid],       (double)ssum[tid]);
        atomicAdd(&stats1[128 + tid], (double)ssq[tid]);
    }
}

// ========== tile-looped pipelined MFMA GEMM (chainB: M2) ==========
template<int K, bool BIAS, bool BNIN, bool STATS, bool STOREB>
__global__ __launch_bounds__(256, 2) void sgemm_loop(
    const __hip_bfloat16* __restrict__ A, const __hip_bfloat16* __restrict__ Wt,
    const float* __restrict__ bias,
    const float* __restrict__ scale, const float* __restrict__ shift,
    double* __restrict__ stats,
    __hip_bfloat16* __restrict__ outb,
    int n, int nt, int grid)
{
    constexpr int NFC = K / 32;
    constexpr int WSLOT = 8 * NFC * 64;
    __shared__ __align__(16) char wlds[WSLOT * 16];
    __shared__ __align__(16) char alds[2][1024 * 16];
    __shared__ float ssum[128], ssq[128];
    const int tid = threadIdx.x, lane = tid & 63, wv = tid >> 6;
    const int l16 = lane & 15, lhi = lane >> 4;

    if (STATS) {
        if (tid < 128) { ssum[tid] = 0.f; ssq[tid] = 0.f; }
    }

#pragma unroll
    for (int i = 0; i < WSLOT / 256; ++i) {
        int slot = tid + i * 256;
        int ln = slot & 63, f = slot >> 6;
        int c = f / NFC, kk = f % NFC;
        int row = c * 16 + (ln & 15);
        int gk = kk * 32 + (ln >> 4) * 8;
        async16(Wt + (size_t)row * K + gk, wlds + slot * 16);
    }

    auto stageA = [&](int tile, int bufi) {
        char* dst = alds[bufi];
#pragma unroll
        for (int i = 0; i < 4; ++i) {
            int slot = tid + i * 256;
            int ln = slot & 63, f = slot >> 6;
            int w = f / NFC, kk = f % NFC;
            int row = tile * 64 + w * 16 + (ln & 15);
            if (row > n - 1) row = n - 1;
            int gk = kk * 32 + (ln >> 4) * 8;
            async16(A + (size_t)row * K + gk, dst + slot * 16);
        }
    };

    auto computeT = [&](int tile, int bufi) {
        const char* ab = alds[bufi];
        f32x4 acc[8];
#pragma unroll
        for (int c = 0; c < 8; ++c)
#pragma unroll
            for (int i = 0; i < 4; ++i) acc[c][i] = 0.f;

#pragma unroll
        for (int kk = 0; kk < NFC; ++kk) {
            bf16x8 a = *reinterpret_cast<const bf16x8*>(
                ab + (((wv * NFC + kk) * 64 + lane) << 4));
            if (BNIN) {
#pragma unroll
                for (int j = 0; j < 8; ++j) {
                    int k = kk * 32 + lhi * 8 + j;
                    a[j] = (__bf16)fmaxf((float)a[j] * scale[k] + shift[k], 0.f);
                }
            }
#pragma unroll
            for (int c = 0; c < 8; ++c) {
                bf16x8 b = *reinterpret_cast<const bf16x8*>(
                    wlds + (((c * NFC + kk) * 64 + lane) << 4));
                acc[c] = __builtin_amdgcn_mfma_f32_16x16x32_bf16(a, b, acc[c], 0, 0, 0);
            }
        }

        const int brow = tile * 64 + wv * 16;
#pragma unroll
        for (int c = 0; c < 8; ++c) {
            const int col = c * 16 + l16;
            const float bv = BIAS ? bias[col] : 0.f;
            float s = 0.f, q = 0.f;
#pragma unroll
            for (int r = 0; r < 4; ++r) {
                int grow = brow + lhi * 4 + r;
                bool ok = grow < n;
                float v = acc[c][r] + bv;
                if (ok) {
                    if (STOREB) outb[(size_t)grow * 128 + col] = __float2bfloat16(v);
                    if (STATS) { s += v; q += v * v; }
                }
            }
            if (STATS) { atomicAdd(&ssum[col], s); atomicAdd(&ssq[col], q); }
        }
    };

    int t = blockIdx.x;
    stageA(t, 0);
    __syncthreads();
    int cur = 0;
    for (; t < nt; t += grid) {
        int tn = t + grid;
        if (tn < nt) stageA(tn, cur ^ 1);
        computeT(t, cur);
        __syncthreads();
        cur ^= 1;
    }

    if (STATS) {
        if (tid < 128) {
            atomicAdd(&stats[tid],       (double)ssum[tid]);
            atomicAdd(&stats[128 + tid], (double)ssq[tid]);
        }
    }
}

// BN finalize -> scale/shift form: relu(a*scale + shift)
__global__ void bn_finalize(const double* __restrict__ stats,
                            const float* __restrict__ g, const float* __restrict__ be,
                            float* __restrict__ scale, float* __restrict__ shift, int n) {
    int c = threadIdx.x;
    if (c < 128) {
        double m = stats[c] / (double)n;
        double var = stats[128 + c] / (double)n - m * m;
        float rs = rsqrtf((float)var + 1e-5f);
        float sc = g[c] * rs;
        scale[c] = sc;
        shift[c] = be[c] - (float)m * sc;
    }
}

// prob = sigmoid( relu(M2*scale+shift) @ Wm3 + bm3 )
__global__ void gemv_prob(const __hip_bfloat16* __restrict__ M2,
                          const float* __restrict__ scale, const float* __restrict__ shift,
                          const float* __restrict__ Wm3, const float* __restrict__ bm3,
                          float* __restrict__ outp, int n) {
    int wid = (int)((blockIdx.x * (size_t)blockDim.x + threadIdx.x) >> 6);
    int lane = threadIdx.x & 63;
    if (wid >= n) return;
    float s = 0.f;
#pragma unroll
    for (int t = 0; t < 2; ++t) {
        int k = lane + t * 64;
        float a = __bfloat162float(M2[(size_t)wid * 128 + k]);
        a = fmaxf(a * scale[k] + shift[k], 0.f);
        s += a * Wm3[k];
    }
#pragma unroll
    for (int off = 32; off > 0; off >>= 1) s += __shfl_down(s, off);
    if (lane == 0) outp[wid] = 1.f / (1.f + __expf(-(s + bm3[0])));
}

extern "C" void kernel_launch(void* const* d_in, const int* in_sizes, int n_in,
                              void* d_out, int out_size, void* d_ws, size_t ws_size,
                              hipStream_t stream) {
    const float* x   = (const float*)d_in[0];
    const int*   pos = (const int*)d_in[1];
    const int*   neg = (const int*)d_in[2];
    const float* W_in = (const float*)d_in[3];
    const float* b_in = (const float*)d_in[4];
    const float* W1p = (const float*)d_in[5];
    const float* b1p = (const float*)d_in[6];
    const float* W1n = (const float*)d_in[7];
    const float* b1n = (const float*)d_in[8];
    const float* W2p = (const float*)d_in[9];
    const float* b2p = (const float*)d_in[10];
    const float* W2n = (const float*)d_in[11];
    const float* b2n = (const float*)d_in[12];
    const float* Wz  = (const float*)d_in[13];
    const float* bz  = (const float*)d_in[14];
    const float* Wm1 = (const float*)d_in[15];
    const float* bm1 = (const float*)d_in[16];
    const float* g1  = (const float*)d_in[17];
    const float* be1 = (const float*)d_in[18];
    const float* Wm2 = (const float*)d_in[19];
    const float* bm2 = (const float*)d_in[20];
    const float* g2  = (const float*)d_in[21];
    const float* be2 = (const float*)d_in[22];
    const float* Wm3 = (const float*)d_in[23];
    const float* bm3 = (const float*)d_in[24];

    char* ws = (char*)d_ws;
    size_t off = 0;
    auto carve = [&](size_t bytes) -> void* {
        void* p = (void*)(ws + off);
        off = (off + bytes + 255) & ~(size_t)255;
        return p;
    };
    const size_t NBH = (size_t)NN * 128 * sizeof(__hip_bfloat16);
    __hip_bfloat16* u1B = (__hip_bfloat16*)carve(NBH);
    __hip_bfloat16* v2B = (__hip_bfloat16*)carve(NBH);
    __hip_bfloat16* z1B = (__hip_bfloat16*)carve(NBH);
    __hip_bfloat16* m1B = (__hip_bfloat16*)carve(NBH);
    __hip_bfloat16* m2B = (__hip_bfloat16*)carve(NBH);
    int* cnt_p = (int*)carve(NN * sizeof(int));
    int* cnt_n = (int*)carve(NN * sizeof(int));
    int* off_p = (int*)carve(NN * sizeof(int));
    int* off_n = (int*)carve(NN * sizeof(int));
    int* cur_p = (int*)carve(NN * sizeof(int));
    int* cur_n = (int*)carve(NN * sizeof(int));
    int* csr_p = (int*)carve(EP * sizeof(int));
    int* csr_n = (int*)carve(EN * sizeof(int));
    int* bsum_p = (int*)carve(1024 * sizeof(int));
    int* bsum_n = (int*)carve(1024 * sizeof(int));
    __hip_bfloat16* Wc1t = (__hip_bfloat16*)carve(128 * 64 * 2);
    __hip_bfloat16* Wc2t = (__hip_bfloat16*)carve(128 * 64 * 2);
    float* bc1 = (float*)carve(128 * sizeof(float));
    float* bc2 = (float*)carve(128 * sizeof(float));
    __hip_bfloat16* Wt2  = (__hip_bfloat16*)carve(128 * 384 * 2);
    __hip_bfloat16* WtZ  = (__hip_bfloat16*)carve(128 * 128 * 2);
    __hip_bfloat16* WtM1 = (__hip_bfloat16*)carve(128 * 128 * 2);
    __hip_bfloat16* WtM2 = (__hip_bfloat16*)carve(128 * 128 * 2);
    float* b2cat = (float*)carve(128 * sizeof(float));
    double* stats1 = (double*)carve(256 * sizeof(double));
    double* stats2 = (double*)carve(256 * sizeof(double));
    float* scale1 = (float*)carve(128 * sizeof(float));
    float* shift1 = (float*)carve(128 * sizeof(float));
    float* scale2 = (float*)carve(128 * sizeof(float));
    float* shift2 = (float*)carve(128 * sizeof(float));
    (void)ws_size; (void)in_sizes; (void)n_in; (void)out_size;

    float* zout = (float*)d_out;                 // N x 128 (fp32)
    float* pout = zout + (size_t)NN * 128;       // N

    const int NT64 = (NN + 63) / 64;             // 2344 tiles
    const int G0   = 512;                        // gemm0 grid (64KB LDS, 2/CU)
    const int GCH  = 512;                        // chainAg grid (81KB LDS, 2/CU)
    const int G128 = 512;                        // chainB grid
    const int NBLK = (NN + SCAN_BS - 1) / SCAN_BS;

    // ---- CSR build + weight prep ----
    hipMemsetAsync(cnt_p, 0, NN * sizeof(int), stream);
    hipMemsetAsync(cnt_n, 0, NN * sizeof(int), stream);
    hipMemsetAsync(stats1, 0, 256 * sizeof(double), stream);
    hipMemsetAsync(stats2, 0, 256 * sizeof(double), stream);
    count_kernel<<<(EP + 255) / 256, 256, 0, stream>>>(pos + EP, EP, cnt_p);
    count_kernel<<<(EN + 255) / 256, 256, 0, stream>>>(neg + EN, EN, cnt_n);
    scan_block<<<NBLK, SCAN_BS, 0, stream>>>(cnt_p, NN, off_p, bsum_p);
    scan_block<<<NBLK, SCAN_BS, 0, stream>>>(cnt_n, NN, off_n, bsum_n);
    scan_bsum<<<1, SCAN_BS, 0, stream>>>(bsum_p, NBLK);
    scan_bsum<<<1, SCAN_BS, 0, stream>>>(bsum_n, NBLK);
    scan_add<<<NBLK, SCAN_BS, 0, stream>>>(bsum_p, NN, off_p, cur_p);
    scan_add<<<NBLK, SCAN_BS, 0, stream>>>(bsum_n, NN, off_n, cur_n);
    fill_csr<<<(EP + 255) / 256, 256, 0, stream>>>(pos, pos + EP, EP, cur_p, csr_p);
    fill_csr<<<(EN + 255) / 256, 256, 0, stream>>>(neg, neg + EN, EN, cur_n, csr_n);
    prep_weights<<<192, 256, 0, stream>>>(W_in, b_in, W1p, b1p, W1n, b1n,
                                          W2p, b2p, W2n, b2n, Wz, Wm1, Wm2,
                                          Wc1t, Wc2t, bc1, bc2,
                                          Wt2, WtZ, WtM1, WtM2, b2cat);

    // GEMM0: x -> U1, V2 (one pass over x)
    gemm0<<<G0, 256, 0, stream>>>(x, Wc1t, bc1, Wc2t, bc2, u1B, v2B, NN, NT64, G0);

    // gather1z: z1 = tanh(aggC + V2)
    gather1z<<<(NN * 16 + 255) / 256, 256, 0, stream>>>(
        u1B, v2B, off_p, cnt_p, csr_p, off_n, cnt_n, csr_n, z1B);

    // chainAg: gather P,Q (LDS-only) -> z2 -> z -> M1 + stats1
    chainAg<<<GCH, 256, 0, stream>>>(
        z1B, off_p, cnt_p, csr_p, off_n, cnt_n, csr_n,
        Wt2, b2cat, WtZ, bz, WtM1, bm1,
        stats1, zout, m1B, NN, NT64, GCH);
    bn_finalize<<<1, 128, 0, stream>>>(stats1, g1, be1, scale1, shift1, NN);

    // chainB: M2 = relu(BN1(M1)) @ WtM2 + bm2 -> m2B + stats2
    sgemm_loop<128, true, true, true, true><<<G128, 256, 0, stream>>>(
        m1B, WtM2, bm2, scale1, shift1, stats2, m2B, NN, NT64, G128);
    bn_finalize<<<1, 128, 0, stream>>>(stats2, g2, be2, scale2, shift2, NN);

    // prob -> d_out tail
    gemv_prob<<<(NN + 3) / 4, 256, 0, stream>>>(m2B, scale2, shift2, Wm3, bm3, pout, NN);
}

// Round 15
// 456.395 us; speedup vs baseline: 1.4295x; 1.4295x over previous
//
#include <hip/hip_runtime.h>
#include <hip/hip_bf16.h>
#include <cstddef>
#include <cstdint>

#define NN 150000
#define EP 400000
#define EN 200000
#define SCAN_BS 256

typedef __bf16 bf16x8 __attribute__((ext_vector_type(8)));
typedef float  f32x4  __attribute__((ext_vector_type(4)));

__device__ __forceinline__ float fast_tanh(float x) {
    float e = __expf(2.f * x);
    return 1.f - 2.f / (e + 1.f);
}

__device__ __forceinline__ void async16(const void* g, void* l) {
    __builtin_amdgcn_global_load_lds(
        (const __attribute__((address_space(1))) void*)g,
        (__attribute__((address_space(3))) void*)l, 16, 0, 0);
}

// ---------------- counts ----------------
__global__ void count_kernel(const int* __restrict__ dst, int E, int* __restrict__ cnt) {
    int e = blockIdx.x * blockDim.x + threadIdx.x;
    if (e < E) atomicAdd(&cnt[dst[e]], 1);
}

// ---------------- exclusive scan (3-kernel) ----------------
__global__ void scan_block(const int* __restrict__ cnt, int n,
                           int* __restrict__ excl, int* __restrict__ bsum) {
    __shared__ int lds[SCAN_BS];
    int tid = threadIdx.x;
    int i = blockIdx.x * SCAN_BS + tid;
    int v = (i < n) ? cnt[i] : 0;
    lds[tid] = v;
    __syncthreads();
    for (int d = 1; d < SCAN_BS; d <<= 1) {
        int t = (tid >= d) ? lds[tid - d] : 0;
        __syncthreads();
        lds[tid] += t;
        __syncthreads();
    }
    if (i < n) excl[i] = lds[tid] - v;
    if (tid == SCAN_BS - 1) bsum[blockIdx.x] = lds[tid];
}

__global__ void scan_bsum(int* __restrict__ bsum, int nb) {
    __shared__ int lds[SCAN_BS];
    __shared__ int carry;
    int tid = threadIdx.x;
    if (tid == 0) carry = 0;
    __syncthreads();
    for (int base = 0; base < nb; base += SCAN_BS) {
        int i = base + tid;
        int v = (i < nb) ? bsum[i] : 0;
        lds[tid] = v;
        __syncthreads();
        for (int d = 1; d < SCAN_BS; d <<= 1) {
            int t = (tid >= d) ? lds[tid - d] : 0;
            __syncthreads();
            lds[tid] += t;
            __syncthreads();
        }
        if (i < nb) bsum[i] = lds[tid] - v + carry;
        __syncthreads();
        if (tid == 0) carry += lds[SCAN_BS - 1];
        __syncthreads();
    }
}

__global__ void scan_add(const int* __restrict__ bsum, int n,
                         int* __restrict__ excl, int* __restrict__ cur) {
    int i = blockIdx.x * SCAN_BS + threadIdx.x;
    if (i < n) {
        int o = excl[i] + bsum[blockIdx.x];
        excl[i] = o;
        cur[i] = o;
    }
}

__global__ void fill_csr(const int* __restrict__ src, const int* __restrict__ dst, int E,
                         int* __restrict__ cur, int* __restrict__ csr) {
    int e = blockIdx.x * blockDim.x + threadIdx.x;
    if (e < E) {
        int d = dst[e];
        int p = atomicAdd(&cur[d], 1);
        csr[p] = src[e];
    }
}

// ---------------- weight prep (incl. algebraic fusion of layer-1) ----------------
__global__ void prep_weights(const float* __restrict__ W_in, const float* __restrict__ b_in,
                             const float* __restrict__ W1p, const float* __restrict__ b1p,
                             const float* __restrict__ W1n, const float* __restrict__ b1n,
                             const float* __restrict__ W2p, const float* __restrict__ b2p,
                             const float* __restrict__ W2n, const float* __restrict__ b2n,
                             const float* __restrict__ Wz,  const float* __restrict__ Wm1,
                             const float* __restrict__ Wm2,
                             __hip_bfloat16* __restrict__ Wc1t,  // [128][64]
                             __hip_bfloat16* __restrict__ Wc2t,  // [128][64]
                             float* __restrict__ bc1, float* __restrict__ bc2,
                             __hip_bfloat16* __restrict__ Wt2,   // [128][384]
                             __hip_bfloat16* __restrict__ WtZ,
                             __hip_bfloat16* __restrict__ WtM1,
                             __hip_bfloat16* __restrict__ WtM2,
                             float* __restrict__ b2cat) {
    int idx = blockIdx.x * blockDim.x + threadIdx.x;
    if (idx < 128 * 64) {
        int c = idx >> 6, k = idx & 63;
        float s1 = 0.f, s2 = 0.f;
#pragma unroll 4
        for (int j = 0; j < 128; ++j) {
            float w = W_in[k * 128 + j];
            float wc = (c < 64) ? W1p[j * 64 + c] : W1n[j * 64 + (c - 64)];
            float wl = (c < 64) ? W1p[(128 + j) * 64 + c] : W1n[(128 + j) * 64 + (c - 64)];
            s1 += w * wc;
            s2 += w * wl;
        }
        Wc1t[idx] = __float2bfloat16(s1);
        Wc2t[idx] = __float2bfloat16(s2);
    }
    if (idx < 128 * 128) {
        int c = idx >> 7, k = idx & 127;
        WtZ[idx]  = __float2bfloat16(Wz[k * 128 + c]);
        WtM1[idx] = __float2bfloat16(Wm1[k * 128 + c]);
        WtM2[idx] = __float2bfloat16(Wm2[k * 128 + c]);
    }
    if (idx < 128 * 384) {
        int c = idx / 384, r = idx % 384;
        float v = 0.f;
        if (r < 64)       { if (c < 64)  v = W2p[r * 64 + c]; }
        else if (r < 128) { if (c >= 64) v = W2n[(r - 64) * 64 + (c - 64)]; }
        else if (r < 192) { if (c >= 64) v = W2n[(64 + r - 128) * 64 + (c - 64)]; }
        else if (r < 256) { if (c < 64)  v = W2p[(64 + r - 192) * 64 + c]; }
        else if (r < 320) { if (c < 64)  v = W2p[(128 + r - 256) * 64 + c]; }
        else              { if (c >= 64) v = W2n[(128 + r - 320) * 64 + (c - 64)]; }
        Wt2[idx] = __float2bfloat16(v);
    }
    if (idx < 128) {
        int c = idx;
        float s1 = 0.f, s2 = 0.f;
#pragma unroll 4
        for (int j = 0; j < 128; ++j) {
            float b = b_in[j];
            float wc = (c < 64) ? W1p[j * 64 + c] : W1n[j * 64 + (c - 64)];
            float wl = (c < 64) ? W1p[(128 + j) * 64 + c] : W1n[(128 + j) * 64 + (c - 64)];
            s1 += b * wc;
            s2 += b * wl;
        }
        bc1[c] = s1;
        bc2[c] = s2 + ((c < 64) ? b1p[c] : b1n[c - 64]);
        b2cat[c] = (c < 64) ? b2p[c] : b2n[c - 64];
    }
}

// ========== GEMM0: x -> U1 (x@Wc1+bc1) AND V2 (x@Wc2+bc2), one A-staging ==========
__global__ __launch_bounds__(256, 2) void gemm0(
    const float* __restrict__ x,
    const __hip_bfloat16* __restrict__ Wc1t, const float* __restrict__ bc1,
    const __hip_bfloat16* __restrict__ Wc2t, const float* __restrict__ bc2,
    __hip_bfloat16* __restrict__ U1, __hip_bfloat16* __restrict__ V2,
    int n, int nt, int grid)
{
    __shared__ __align__(16) char w1lds[1024 * 16];
    __shared__ __align__(16) char w2lds[1024 * 16];
    __shared__ __align__(16) char alds[2][1024 * 16];
    const int tid = threadIdx.x, lane = tid & 63, wv = tid >> 6;
    const int l16 = lane & 15, lhi = lane >> 4;

#pragma unroll
    for (int i = 0; i < 4; ++i) {
        int slot = tid + i * 256;
        int ln = slot & 63, f = slot >> 6;
        int c = f >> 1, kk = f & 1;
        int row = c * 16 + (ln & 15);
        int gk = kk * 32 + (ln >> 4) * 8;
        async16(Wc1t + (size_t)row * 64 + gk, w1lds + slot * 16);
        async16(Wc2t + (size_t)row * 64 + gk, w2lds + slot * 16);
    }

    auto stageA = [&](int tile, int bufi) {
        char* dst = alds[bufi];
#pragma unroll
        for (int i = 0; i < 4; ++i) {
            int slot = tid + i * 256;
            int ln = slot & 63, f = slot >> 6;
            int w = f >> 2, kk = (f >> 1) & 1, half = f & 1;
            int row = tile * 64 + w * 16 + (ln & 15);
            if (row > n - 1) row = n - 1;
            int k = kk * 32 + (ln >> 4) * 8 + half * 4;
            async16(x + (size_t)row * 64 + k, dst + slot * 16);
        }
    };

    auto computeT = [&](int tile, int bufi) {
        const char* ab = alds[bufi];
        bf16x8 afr[2];
#pragma unroll
        for (int kk = 0; kk < 2; ++kk) {
            f32x4 lo = *reinterpret_cast<const f32x4*>(
                ab + ((((wv * 2 + kk) * 2 + 0) * 64 + lane) << 4));
            f32x4 hi = *reinterpret_cast<const f32x4*>(
                ab + ((((wv * 2 + kk) * 2 + 1) * 64 + lane) << 4));
            bf16x8 a;
            a[0] = (__bf16)lo[0]; a[1] = (__bf16)lo[1];
            a[2] = (__bf16)lo[2]; a[3] = (__bf16)lo[3];
            a[4] = (__bf16)hi[0]; a[5] = (__bf16)hi[1];
            a[6] = (__bf16)hi[2]; a[7] = (__bf16)hi[3];
            afr[kk] = a;
        }
        const int brow = tile * 64 + wv * 16;
#pragma unroll
        for (int half = 0; half < 2; ++half) {
            const char* wl = half ? w2lds : w1lds;
            const float* bias = half ? bc2 : bc1;
            __hip_bfloat16* out = half ? V2 : U1;
            f32x4 acc[8];
#pragma unroll
            for (int c = 0; c < 8; ++c)
#pragma unroll
                for (int i = 0; i < 4; ++i) acc[c][i] = 0.f;
#pragma unroll
            for (int kk = 0; kk < 2; ++kk)
#pragma unroll
                for (int c = 0; c < 8; ++c) {
                    bf16x8 b = *reinterpret_cast<const bf16x8*>(
                        wl + (((c * 2 + kk) * 64 + lane) << 4));
                    acc[c] = __builtin_amdgcn_mfma_f32_16x16x32_bf16(afr[kk], b, acc[c], 0, 0, 0);
                }
#pragma unroll
            for (int c = 0; c < 8; ++c) {
                int col = c * 16 + l16;
                float bv = bias[col];
#pragma unroll
                for (int r = 0; r < 4; ++r) {
                    int grow = brow + lhi * 4 + r;
                    if (grow < n)
                        out[(size_t)grow * 128 + col] = __float2bfloat16(acc[c][r] + bv);
                }
            }
        }
    };

    int t = blockIdx.x;
    stageA(t, 0);
    __syncthreads();
    int cur = 0;
    for (; t < nt; t += grid) {
        int tn = t + grid;
        if (tn < nt) stageA(tn, cur ^ 1);
        computeT(t, cur);
        __syncthreads();
        cur ^= 1;
    }
}

// ======= gather1z: z1 = tanh(aggC + V2), aggC gathered from U1 via CSR =======
__global__ void gather1z(const __hip_bfloat16* __restrict__ U1,
                         const __hip_bfloat16* __restrict__ V2,
                         const int* __restrict__ offp, const int* __restrict__ cntp,
                         const int* __restrict__ csrp,
                         const int* __restrict__ offn, const int* __restrict__ cntn,
                         const int* __restrict__ csrn,
                         __hip_bfloat16* __restrict__ z1) {
    int gid = blockIdx.x * blockDim.x + threadIdx.x;
    if (gid >= NN * 16) return;
    int d = gid >> 4, cg = gid & 15;
    int c0 = cg * 8;
    const int* off; const int* cnt; const int* csr;
    if (cg < 8) { off = offp; cnt = cntp; csr = csrp; }
    else        { off = offn; cnt = cntn; csr = csrn; }
    int o = off[d], dg = cnt[d];
    float acc[8] = {0.f, 0.f, 0.f, 0.f, 0.f, 0.f, 0.f, 0.f};
    for (int e = 0; e < dg; ++e) {
        int s = csr[o + e];
        bf16x8 v = *reinterpret_cast<const bf16x8*>(&U1[(size_t)s * 128 + c0]);
#pragma unroll
        for (int j = 0; j < 8; ++j) acc[j] += (float)v[j];
    }
    float inv = 1.f / (float)(dg > 0 ? dg : 1);
    bf16x8 v2 = *reinterpret_cast<const bf16x8*>(&V2[(size_t)d * 128 + c0]);
    bf16x8 r;
#pragma unroll
    for (int j = 0; j < 8; ++j)
        r[j] = (__bf16)fast_tanh(acc[j] * inv + (float)v2[j]);
    *reinterpret_cast<bf16x8*>(&z1[(size_t)d * 128 + c0]) = r;
}

// ---------------- gather2v: P = mean_pos(z1), Q = mean_neg(z1) ----------------
__global__ void gather2v(const __hip_bfloat16* __restrict__ z1,
                         const int* __restrict__ offp, const int* __restrict__ cntp,
                         const int* __restrict__ csrp,
                         const int* __restrict__ offn, const int* __restrict__ cntn,
                         const int* __restrict__ csrn,
                         __hip_bfloat16* __restrict__ P, __hip_bfloat16* __restrict__ Q) {
    int gid = blockIdx.x * blockDim.x + threadIdx.x;
    if (gid >= NN * 32) return;
    int d = gid >> 5, cg = gid & 31;
    const int* off; const int* cnt; const int* csr; __hip_bfloat16* out; int c0;
    if (cg < 16) { off = offp; cnt = cntp; csr = csrp; out = P; c0 = cg * 8; }
    else         { off = offn; cnt = cntn; csr = csrn; out = Q; c0 = (cg - 16) * 8; }
    int o = off[d], dg = cnt[d];
    float acc[8] = {0.f, 0.f, 0.f, 0.f, 0.f, 0.f, 0.f, 0.f};
    for (int e = 0; e < dg; ++e) {
        int s = csr[o + e];
        bf16x8 v = *reinterpret_cast<const bf16x8*>(&z1[(size_t)s * 128 + c0]);
#pragma unroll
        for (int j = 0; j < 8; ++j) acc[j] += (float)v[j];
    }
    float inv = 1.f / (float)(dg > 0 ? dg : 1);
    bf16x8 r;
#pragma unroll
    for (int j = 0; j < 8; ++j) r[j] = (__bf16)(acc[j] * inv);
    *reinterpret_cast<bf16x8*>(&out[(size_t)d * 128 + c0]) = r;
}

// ========= chainA_v2: per 64-row tile: z2 -> z -> M1, two-half W buffer =========
// 64KB wlds = two 32KB halves, each stage-drain delivers TWO W chunks -> 3 drains,
// 6 barriers per tile (vs 5/9 in v1). z2/z LDS-only (swizzled 16KB). BN stats in
// registers, shfl-reduced at kernel end. LDS exactly 80KB -> 2 blocks/CU.
__global__ __launch_bounds__(256, 2) void chainA2(
    const __hip_bfloat16* __restrict__ P, const __hip_bfloat16* __restrict__ Q,
    const __hip_bfloat16* __restrict__ z1,
    const __hip_bfloat16* __restrict__ Wt2, const float* __restrict__ b2cat,
    const __hip_bfloat16* __restrict__ WtZ, const float* __restrict__ bz,
    const __hip_bfloat16* __restrict__ WtM1, const float* __restrict__ bm1,
    double* __restrict__ stats1, float* __restrict__ zout,
    __hip_bfloat16* __restrict__ m1B, int n, int nt, int grid)
{
    __shared__ __align__(16) char wlds[2 * 32768];   // 64KB: two 128-wide W chunks
    __shared__ __align__(16) char zlds[64 * 256];    // 16KB: z2 then z (swizzled)
    const int tid = threadIdx.x, lane = tid & 63, wv = tid >> 6;
    const int l16 = lane & 15, lhi = lane >> 4;

    auto stageW = [&](const __hip_bfloat16* Wt, int ks, int k0, int half) {
#pragma unroll
        for (int i = 0; i < 8; ++i) {
            int slot = tid + i * 256;
            int ln = slot & 63, f = slot >> 6;
            int c = f >> 2, kk = f & 3;
            int row = c * 16 + (ln & 15);
            int gk = k0 + kk * 32 + (ln >> 4) * 8;
            async16(Wt + (size_t)row * ks + gk, wlds + half * 32768 + slot * 16);
        }
    };
    auto domfma = [&](const bf16x8 (&af)[4], f32x4 (&acc)[8], int half) {
        const char* base = wlds + half * 32768;
#pragma unroll
        for (int kk = 0; kk < 4; ++kk)
#pragma unroll
            for (int c = 0; c < 8; ++c) {
                bf16x8 b = *reinterpret_cast<const bf16x8*>(
                    base + (((c * 4 + kk) * 64 + lane) << 4));
                acc[c] = __builtin_amdgcn_mfma_f32_16x16x32_bf16(af[kk], b, acc[c], 0, 0, 0);
            }
    };
    auto zacc = [&](f32x4 (&acc)[8]) {
#pragma unroll
        for (int c = 0; c < 8; ++c)
#pragma unroll
            for (int i = 0; i < 4; ++i) acc[c][i] = 0.f;
    };
    auto ld_t = [&](bf16x8 (&af)[4]) {
        int rl = wv * 16 + l16;
#pragma unroll
        for (int kk = 0; kk < 4; ++kk) {
            int byte = rl * 256 + ((kk * 64 + lhi * 16) ^ ((rl & 7) << 4));
            af[kk] = *reinterpret_cast<const bf16x8*>(zlds + byte);
        }
    };
    auto st_z = [&](int rl, int col, float v) {
        int byte = rl * 256 + ((col * 2) ^ ((rl & 7) << 4));
        *reinterpret_cast<__hip_bfloat16*>(zlds + byte) = __float2bfloat16(v);
    };

    float sreg[8], qreg[8];
#pragma unroll
    for (int c = 0; c < 8; ++c) { sreg[c] = 0.f; qreg[c] = 0.f; }

    bf16x8 af[4];
    f32x4 acc[8];

    for (int t = blockIdx.x; t < nt; t += grid) {
        int arow = t * 64 + wv * 16 + l16; if (arow > n - 1) arow = n - 1;

        // issue W chunks 0+1 and all A-frag loads, one drain
        stageW(Wt2, 384, 0, 0);
        stageW(Wt2, 384, 128, 1);
        bf16x8 aP[4], aQ[4], aZ[4];
#pragma unroll
        for (int kk = 0; kk < 4; ++kk) {
            aP[kk] = *reinterpret_cast<const bf16x8*>(P  + (size_t)arow * 128 + kk * 32 + lhi * 8);
            aQ[kk] = *reinterpret_cast<const bf16x8*>(Q  + (size_t)arow * 128 + kk * 32 + lhi * 8);
            aZ[kk] = *reinterpret_cast<const bf16x8*>(z1 + (size_t)arow * 128 + kk * 32 + lhi * 8);
        }
        __syncthreads();                          // B1: drain stages (+loads)

        zacc(acc);
        domfma(aP, acc, 0);
        domfma(aQ, acc, 1);
        __syncthreads();                          // B2: wlds reads done

        stageW(Wt2, 384, 256, 0);
        stageW(WtZ, 128, 0, 1);
        __syncthreads();                          // B3: drained

        // z2 = tanh([P|Q|z1] @ Wt2 + b2cat) -> zlds
        domfma(aZ, acc, 0);
#pragma unroll
        for (int c = 0; c < 8; ++c) {
            int col = c * 16 + l16;
            float bv = b2cat[col];
#pragma unroll
            for (int r = 0; r < 4; ++r)
                st_z(wv * 16 + lhi * 4 + r, col, fast_tanh(acc[c][r] + bv));
        }
        // z = tanh(z2 @ WtZ + bz) -> zout + zlds  (own-strip LDS, wave-local order)
        zacc(acc);
        ld_t(af);
        domfma(af, acc, 1);
#pragma unroll
        for (int c = 0; c < 8; ++c) {
            int col = c * 16 + l16;
            float bv = bz[col];
#pragma unroll
            for (int r = 0; r < 4; ++r) {
                int rl = wv * 16 + lhi * 4 + r;
                int grow = t * 64 + rl;
                float v = fast_tanh(acc[c][r] + bv);
                if (grow < n) zout[(size_t)grow * 128 + col] = v;
                st_z(rl, col, v);
            }
        }
        __syncthreads();                          // B4: wlds reads done

        stageW(WtM1, 128, 0, 0);
        __syncthreads();                          // B5: drained

        // M1 = z @ WtM1 + bm1 -> m1B + reg stats
        zacc(acc);
        ld_t(af);
        domfma(af, acc, 0);
#pragma unroll
        for (int c = 0; c < 8; ++c) {
            int col = c * 16 + l16;
            float bv = bm1[col];
#pragma unroll
            for (int r = 0; r < 4; ++r) {
                int rl = wv * 16 + lhi * 4 + r;
                int grow = t * 64 + rl;
                float v = acc[c][r] + bv;
                if (grow < n) {
                    m1B[(size_t)grow * 128 + col] = __float2bfloat16(v);
                    sreg[c] += v;
                    qreg[c] += v * v;
                }
            }
        }
        __syncthreads();                          // B6: wlds/zlds reads done before next tile
    }

    // reduce stats over lhi (lanes ^16, ^32 share the same column set)
#pragma unroll
    for (int c = 0; c < 8; ++c) {
        float s = sreg[c], q = qreg[c];
        s += __shfl_xor(s, 16); s += __shfl_xor(s, 32);
        q += __shfl_xor(q, 16); q += __shfl_xor(q, 32);
        if (lane < 16) {
            atomicAdd(&stats1[c * 16 + lane],       (double)s);
            atomicAdd(&stats1[128 + c * 16 + lane], (double)q);
        }
    }
}

// ========== tile-looped pipelined MFMA GEMM (chainB: M2) ==========
template<int K, bool BIAS, bool BNIN, bool STATS, bool STOREB>
__global__ __launch_bounds__(256, 2) void sgemm_loop(
    const __hip_bfloat16* __restrict__ A, const __hip_bfloat16* __restrict__ Wt,
    const float* __restrict__ bias,
    const float* __restrict__ scale, const float* __restrict__ shift,
    double* __restrict__ stats,
    __hip_bfloat16* __restrict__ outb,
    int n, int nt, int grid)
{
    constexpr int NFC = K / 32;
    constexpr int WSLOT = 8 * NFC * 64;
    __shared__ __align__(16) char wlds[WSLOT * 16];
    __shared__ __align__(16) char alds[2][1024 * 16];
    __shared__ float ssum[128], ssq[128];
    const int tid = threadIdx.x, lane = tid & 63, wv = tid >> 6;
    const int l16 = lane & 15, lhi = lane >> 4;

    if (STATS) {
        if (tid < 128) { ssum[tid] = 0.f; ssq[tid] = 0.f; }
    }

#pragma unroll
    for (int i = 0; i < WSLOT / 256; ++i) {
        int slot = tid + i * 256;
        int ln = slot & 63, f = slot >> 6;
        int c = f / NFC, kk = f % NFC;
        int row = c * 16 + (ln & 15);
        int gk = kk * 32 + (ln >> 4) * 8;
        async16(Wt + (size_t)row * K + gk, wlds + slot * 16);
    }

    auto stageA = [&](int tile, int bufi) {
        char* dst = alds[bufi];
#pragma unroll
        for (int i = 0; i < 4; ++i) {
            int slot = tid + i * 256;
            int ln = slot & 63, f = slot >> 6;
            int w = f / NFC, kk = f % NFC;
            int row = tile * 64 + w * 16 + (ln & 15);
            if (row > n - 1) row = n - 1;
            int gk = kk * 32 + (ln >> 4) * 8;
            async16(A + (size_t)row * K + gk, dst + slot * 16);
        }
    };

    auto computeT = [&](int tile, int bufi) {
        const char* ab = alds[bufi];
        f32x4 acc[8];
#pragma unroll
        for (int c = 0; c < 8; ++c)
#pragma unroll
            for (int i = 0; i < 4; ++i) acc[c][i] = 0.f;

#pragma unroll
        for (int kk = 0; kk < NFC; ++kk) {
            bf16x8 a = *reinterpret_cast<const bf16x8*>(
                ab + (((wv * NFC + kk) * 64 + lane) << 4));
            if (BNIN) {
#pragma unroll
                for (int j = 0; j < 8; ++j) {
                    int k = kk * 32 + lhi * 8 + j;
                    a[j] = (__bf16)fmaxf((float)a[j] * scale[k] + shift[k], 0.f);
                }
            }
#pragma unroll
            for (int c = 0; c < 8; ++c) {
                bf16x8 b = *reinterpret_cast<const bf16x8*>(
                    wlds + (((c * NFC + kk) * 64 + lane) << 4));
                acc[c] = __builtin_amdgcn_mfma_f32_16x16x32_bf16(a, b, acc[c], 0, 0, 0);
            }
        }

        const int brow = tile * 64 + wv * 16;
#pragma unroll
        for (int c = 0; c < 8; ++c) {
            const int col = c * 16 + l16;
            const float bv = BIAS ? bias[col] : 0.f;
            float s = 0.f, q = 0.f;
#pragma unroll
            for (int r = 0; r < 4; ++r) {
                int grow = brow + lhi * 4 + r;
                bool ok = grow < n;
                float v = acc[c][r] + bv;
                if (ok) {
                    if (STOREB) outb[(size_t)grow * 128 + col] = __float2bfloat16(v);
                    if (STATS) { s += v; q += v * v; }
                }
            }
            if (STATS) { atomicAdd(&ssum[col], s); atomicAdd(&ssq[col], q); }
        }
    };

    int t = blockIdx.x;
    stageA(t, 0);
    __syncthreads();
    int cur = 0;
    for (; t < nt; t += grid) {
        int tn = t + grid;
        if (tn < nt) stageA(tn, cur ^ 1);
        computeT(t, cur);
        __syncthreads();
        cur ^= 1;
    }

    if (STATS) {
        if (tid < 128) {
            atomicAdd(&stats[tid],       (double)ssum[tid]);
            atomicAdd(&stats[128 + tid], (double)ssq[tid]);
        }
    }
}

// BN finalize -> scale/shift form: relu(a*scale + shift)
__global__ void bn_finalize(const double* __restrict__ stats,
                            const float* __restrict__ g, const float* __restrict__ be,
                            float* __restrict__ scale, float* __restrict__ shift, int n) {
    int c = threadIdx.x;
    if (c < 128) {
        double m = stats[c] / (double)n;
        double var = stats[128 + c] / (double)n - m * m;
        float rs = rsqrtf((float)var + 1e-5f);
        float sc = g[c] * rs;
        scale[c] = sc;
        shift[c] = be[c] - (float)m * sc;
    }
}

// prob = sigmoid( relu(M2*scale+shift) @ Wm3 + bm3 )
__global__ void gemv_prob(const __hip_bfloat16* __restrict__ M2,
                          const float* __restrict__ scale, const float* __restrict__ shift,
                          const float* __restrict__ Wm3, const float* __restrict__ bm3,
                          float* __restrict__ outp, int n) {
    int wid = (int)((blockIdx.x * (size_t)blockDim.x + threadIdx.x) >> 6);
    int lane = threadIdx.x & 63;
    if (wid >= n) return;
    float s = 0.f;
#pragma unroll
    for (int t = 0; t < 2; ++t) {
        int k = lane + t * 64;
        float a = __bfloat162float(M2[(size_t)wid * 128 + k]);
        a = fmaxf(a * scale[k] + shift[k], 0.f);
        s += a * Wm3[k];
    }
#pragma unroll
    for (int off = 32; off > 0; off >>= 1) s += __shfl_down(s, off);
    if (lane == 0) outp[wid] = 1.f / (1.f + __expf(-(s + bm3[0])));
}

extern "C" void kernel_launch(void* const* d_in, const int* in_sizes, int n_in,
                              void* d_out, int out_size, void* d_ws, size_t ws_size,
                              hipStream_t stream) {
    const float* x   = (const float*)d_in[0];
    const int*   pos = (const int*)d_in[1];
    const int*   neg = (const int*)d_in[2];
    const float* W_in = (const float*)d_in[3];
    const float* b_in = (const float*)d_in[4];
    const float* W1p = (const float*)d_in[5];
    const float* b1p = (const float*)d_in[6];
    const float* W1n = (const float*)d_in[7];
    const float* b1n = (const float*)d_in[8];
    const float* W2p = (const float*)d_in[9];
    const float* b2p = (const float*)d_in[10];
    const float* W2n = (const float*)d_in[11];
    const float* b2n = (const float*)d_in[12];
    const float* Wz  = (const float*)d_in[13];
    const float* bz  = (const float*)d_in[14];
    const float* Wm1 = (const float*)d_in[15];
    const float* bm1 = (const float*)d_in[16];
    const float* g1  = (const float*)d_in[17];
    const float* be1 = (const float*)d_in[18];
    const float* Wm2 = (const float*)d_in[19];
    const float* bm2 = (const float*)d_in[20];
    const float* g2  = (const float*)d_in[21];
    const float* be2 = (const float*)d_in[22];
    const float* Wm3 = (const float*)d_in[23];
    const float* bm3 = (const float*)d_in[24];

    char* ws = (char*)d_ws;
    size_t off = 0;
    auto carve = [&](size_t bytes) -> void* {
        void* p = (void*)(ws + off);
        off = (off + bytes + 255) & ~(size_t)255;
        return p;
    };
    const size_t NBH = (size_t)NN * 128 * sizeof(__hip_bfloat16);
    __hip_bfloat16* u1B = (__hip_bfloat16*)carve(NBH);   // U1, then P
    __hip_bfloat16* v2B = (__hip_bfloat16*)carve(NBH);   // V2, then Q
    __hip_bfloat16* z1B = (__hip_bfloat16*)carve(NBH);
    __hip_bfloat16* m1B = (__hip_bfloat16*)carve(NBH);
    __hip_bfloat16* m2B = (__hip_bfloat16*)carve(NBH);
    int* cnt_p = (int*)carve(NN * sizeof(int));
    int* cnt_n = (int*)carve(NN * sizeof(int));
    int* off_p = (int*)carve(NN * sizeof(int));
    int* off_n = (int*)carve(NN * sizeof(int));
    int* cur_p = (int*)carve(NN * sizeof(int));
    int* cur_n = (int*)carve(NN * sizeof(int));
    int* csr_p = (int*)carve(EP * sizeof(int));
    int* csr_n = (int*)carve(EN * sizeof(int));
    int* bsum_p = (int*)carve(1024 * sizeof(int));
    int* bsum_n = (int*)carve(1024 * sizeof(int));
    __hip_bfloat16* Wc1t = (__hip_bfloat16*)carve(128 * 64 * 2);
    __hip_bfloat16* Wc2t = (__hip_bfloat16*)carve(128 * 64 * 2);
    float* bc1 = (float*)carve(128 * sizeof(float));
    float* bc2 = (float*)carve(128 * sizeof(float));
    __hip_bfloat16* Wt2  = (__hip_bfloat16*)carve(128 * 384 * 2);
    __hip_bfloat16* WtZ  = (__hip_bfloat16*)carve(128 * 128 * 2);
    __hip_bfloat16* WtM1 = (__hip_bfloat16*)carve(128 * 128 * 2);
    __hip_bfloat16* WtM2 = (__hip_bfloat16*)carve(128 * 128 * 2);
    float* b2cat = (float*)carve(128 * sizeof(float));
    double* stats1 = (double*)carve(256 * sizeof(double));
    double* stats2 = (double*)carve(256 * sizeof(double));
    float* scale1 = (float*)carve(128 * sizeof(float));
    float* shift1 = (float*)carve(128 * sizeof(float));
    float* scale2 = (float*)carve(128 * sizeof(float));
    float* shift2 = (float*)carve(128 * sizeof(float));
    (void)ws_size; (void)in_sizes; (void)n_in; (void)out_size;

    float* zout = (float*)d_out;                 // N x 128 (fp32)
    float* pout = zout + (size_t)NN * 128;       // N

    const int NT64 = (NN + 63) / 64;             // 2344 tiles
    const int G0   = 512;
    const int GCH  = 512;
    const int G128 = 512;
    const int NBLK = (NN + SCAN_BS - 1) / SCAN_BS;

    // ---- CSR build + weight prep ----
    hipMemsetAsync(cnt_p, 0, NN * sizeof(int), stream);
    hipMemsetAsync(cnt_n, 0, NN * sizeof(int), stream);
    hipMemsetAsync(stats1, 0, 256 * sizeof(double), stream);
    hipMemsetAsync(stats2, 0, 256 * sizeof(double), stream);
    count_kernel<<<(EP + 255) / 256, 256, 0, stream>>>(pos + EP, EP, cnt_p);
    count_kernel<<<(EN + 255) / 256, 256, 0, stream>>>(neg + EN, EN, cnt_n);
    scan_block<<<NBLK, SCAN_BS, 0, stream>>>(cnt_p, NN, off_p, bsum_p);
    scan_block<<<NBLK, SCAN_BS, 0, stream>>>(cnt_n, NN, off_n, bsum_n);
    scan_bsum<<<1, SCAN_BS, 0, stream>>>(bsum_p, NBLK);
    scan_bsum<<<1, SCAN_BS, 0, stream>>>(bsum_n, NBLK);
    scan_add<<<NBLK, SCAN_BS, 0, stream>>>(bsum_p, NN, off_p, cur_p);
    scan_add<<<NBLK, SCAN_BS, 0, stream>>>(bsum_n, NN, off_n, cur_n);
    fill_csr<<<(EP + 255) / 256, 256, 0, stream>>>(pos, pos + EP, EP, cur_p, csr_p);
    fill_csr<<<(EN + 255) / 256, 256, 0, stream>>>(neg, neg + EN, EN, cur_n, csr_n);
    prep_weights<<<192, 256, 0, stream>>>(W_in, b_in, W1p, b1p, W1n, b1n,
                                          W2p, b2p, W2n, b2n, Wz, Wm1, Wm2,
                                          Wc1t, Wc2t, bc1, bc2,
                                          Wt2, WtZ, WtM1, WtM2, b2cat);

    // GEMM0: x -> U1, V2 (one pass over x)
    gemm0<<<G0, 256, 0, stream>>>(x, Wc1t, bc1, Wc2t, bc2, u1B, v2B, NN, NT64, G0);

    // gather1z: z1 = tanh(aggC + V2)
    gather1z<<<(NN * 16 + 255) / 256, 256, 0, stream>>>(
        u1B, v2B, off_p, cnt_p, csr_p, off_n, cnt_n, csr_n, z1B);

    // gather2v: P, Q (reuse u1B/v2B — U1,V2 dead)
    gather2v<<<(NN * 32 + 255) / 256, 256, 0, stream>>>(
        z1B, off_p, cnt_p, csr_p, off_n, cnt_n, csr_n, u1B, v2B);

    // chainA2: z2 -> z -> M1 (z2/z LDS-only) -> zout, m1B, stats1
    chainA2<<<GCH, 256, 0, stream>>>(
        u1B, v2B, z1B, Wt2, b2cat, WtZ, bz, WtM1, bm1,
        stats1, zout, m1B, NN, NT64, GCH);
    bn_finalize<<<1, 128, 0, stream>>>(stats1, g1, be1, scale1, shift1, NN);

    // chainB: M2 = relu(BN1(M1)) @ WtM2 + bm2 -> m2B + stats2
    sgemm_loop<128, true, true, true, true><<<G128, 256, 0, stream>>>(
        m1B, WtM2, bm2, scale1, shift1, stats2, m2B, NN, NT64, G128);
    bn_finalize<<<1, 128, 0, stream>>>(stats2, g2, be2, scale2, shift2, NN);

    // prob -> d_out tail
    gemv_prob<<<(NN + 3) / 4, 256, 0, stream>>>(m2B, scale2, shift2, Wm3, bm3, pout, NN);
}